// Round 2
// baseline (152.158 us; speedup 1.0000x reference)
//
#include <hip/hip_runtime.h>
#include <cstdint>

// Head attention: x[4,4096,1024] fp32, Wq/Wk/Wv[1024,64] fp32 -> out[4,4096,64] fp32.
// Round 11: round-10 2-phase prefetch template with the LDS sizing bug fixed:
// per-buffer slab sizes restored to 8KB (x) / 24KB (w) -- r10 had halved them
// (the leading '2' in r9's arrays was the sub-step dim, not a dbuf dim).
//  K0: wt_prep  - W -> bf16 per-64k-step LDS-image slabs; Wq pre-scaled (frozen)
//  K1: qkv_proj - 32-row blocks, BK=64, staggered slab phase, dbuf prefetch pipeline
//  K2: flash    - item (b, qt64, h4): 64 q-rows, dbuf 16KB KV slab prefetch pipeline
//  K3: combine  - out = sum_h O_h / sum_h l_h, 512 blocks x 32 rows

typedef __bf16 bf16;
typedef __bf16 bf16x8 __attribute__((ext_vector_type(8)));
typedef float  f32x4  __attribute__((ext_vector_type(4)));

#define MFMA16(a, b, c) __builtin_amdgcn_mfma_f32_16x16x32_bf16((a), (b), (c), 0, 0, 0)

#if __has_builtin(__builtin_amdgcn_exp2f)
#define EXP2(x) __builtin_amdgcn_exp2f(x)
#else
#define EXP2(x) exp2f(x)
#endif

#define B_SZ 4
#define T_SZ 4096
#define C_SZ 1024
#define H_SZ 64
#define M_SZ (B_SZ * T_SZ)
#define QSCALE (1.4426950408889634f / 32.0f)   // log2(e)/sqrt(1024)
#define P_STR 4160                             // floats per partial: 64x64 O + 64 l

// async 16B global->LDS DMA; LDS dest is wave-uniform base + lane*16.
__device__ __forceinline__ void dma16(const void* g, void* l) {
    __builtin_amdgcn_global_load_lds(
        (const __attribute__((address_space(1))) uint32_t*)(uintptr_t)g,
        (__attribute__((address_space(3))) uint32_t*)(uint32_t)(uintptr_t)l,
        16, 0, 0);
}

// bottom-of-iter pipeline sync: drain own prefetch DMAs, sync block, pin sched.
__device__ __forceinline__ void pipe_sync() {
    asm volatile("s_waitcnt vmcnt(0)" ::: "memory");
    __builtin_amdgcn_s_barrier();
    __builtin_amdgcn_sched_barrier(0);
}

// -------------------------------------------------------------------------
// K0: wt2 image, per 64-k outer step s: elem off =
//   s*12288 + sub*6144 + quad*1536 + n*8 + j  (k = s*64+sub*32+quad*8+j, n = 0..191).
// -------------------------------------------------------------------------
__global__ __launch_bounds__(256) void wt_prep(
    const float* __restrict__ Wq, const float* __restrict__ Wk,
    const float* __restrict__ Wv, bf16* __restrict__ wt2)
{
    const int n4 = blockIdx.x, t = threadIdx.x;
    const int nbase = n4 * 4;
    const float* W = (nbase < 64) ? Wq : (nbase < 128 ? Wk : Wv);
    const float sc = (nbase < 64) ? QSCALE : 1.0f;
    const int ncol = nbase & 63;
    #pragma unroll
    for (int i = 0; i < 4; ++i) {
        const int k = i * 256 + t;
        const float4 v = *(const float4*)(W + (size_t)k * H_SZ + ncol);
        const float vals[4] = {v.x, v.y, v.z, v.w};
        const size_t base = (size_t)(k >> 6) * 12288 + (size_t)((k >> 5) & 1) * 6144
                          + (size_t)((k >> 3) & 3) * 1536 + (k & 7);
        #pragma unroll
        for (int m = 0; m < 4; ++m)
            wt2[base + (size_t)(nbase + m) * 8] = (bf16)(vals[m] * sc);
    }
}

// -------------------------------------------------------------------------
// K1: qkv. grid 512 x 256 (4 waves). Block = 32 rows x 192 fused cols.
// 16 steps of BK=64, slab phase staggered by block. Double-buffered slabs
// (each buffer: x 8KB = [sub2][quad4][row32][8f], w 24KB): stage step s+1 at
// top, compute step s, one vmcnt(0)+s_barrier at bottom. LDS total 64KB.
// -------------------------------------------------------------------------
__global__ __launch_bounds__(256) void qkv_proj(
    const float* __restrict__ x, const bf16* __restrict__ wt2,
    bf16* __restrict__ qw, bf16* __restrict__ kw2, bf16* __restrict__ vtw2)
{
    const int m0 = blockIdx.x * 32;
    const int tid = threadIdx.x;
    const int wave = tid >> 6, lane = tid & 63;
    const int quad = lane >> 4, l15 = lane & 15;
    const int phase = blockIdx.x & 15;             // slab-phase stagger

    __shared__ __align__(16) float xs[2][2 * 4 * 32 * 8];   // 2 x 8 KB
    __shared__ __align__(16) bf16  ws[2][2 * 4 * 192 * 8];  // 2 x 24 KB

    f32x4 acc[2][3] = {};                          // [mg][ntile]

    // x DMA granule (per thread, i in {0,1}): sub=i, quad=(tid>>6)&3,
    // row=(tid>>1)&31, half=tid&1. k-offset within step: sub*128B+quad*32B+half*16B.
    const char* xg = (const char*)x
        + (size_t)(m0 + ((tid >> 1) & 31)) * 4096
        + (size_t)((tid >> 6) & 3) * 32 + (size_t)(tid & 1) * 16;
    const char* wg = (const char*)wt2 + (size_t)tid * 16;

    auto stage = [&](int s, int buf) {
        const size_t se = (size_t)((s + phase) & 15);
        char* xl = (char*)(&xs[buf][0]) + (size_t)tid * 16;
        char* wl = (char*)(&ws[buf][0]) + (size_t)tid * 16;
        dma16(xg + se * 256, xl);
        dma16(xg + se * 256 + 128, xl + 4096);
        #pragma unroll
        for (int i = 0; i < 6; ++i)
            dma16(wg + se * 24576 + (size_t)i * 4096, wl + (size_t)i * 4096);
    };

    stage(0, 0);
    pipe_sync();                                   // buf0 ready

    for (int s = 0; s < 16; ++s) {
        if (s < 15) stage(s + 1, (s + 1) & 1);     // prefetch next slab pair
        const float* xb = &xs[s & 1][0];
        const bf16*  wb = &ws[s & 1][0];

        #pragma unroll
        for (int ss = 0; ss < 2; ++ss) {
            bf16x8 a[2];
            #pragma unroll
            for (int mg = 0; mg < 2; ++mg) {
                const float* ap = xb + ss * 1024 + quad * 256 + (mg * 16 + l15) * 8;
                const f32x4 lo = *(const f32x4*)ap;
                const f32x4 hi = *(const f32x4*)(ap + 4);
                a[mg][0] = (bf16)lo[0]; a[mg][1] = (bf16)lo[1];
                a[mg][2] = (bf16)lo[2]; a[mg][3] = (bf16)lo[3];
                a[mg][4] = (bf16)hi[0]; a[mg][5] = (bf16)hi[1];
                a[mg][6] = (bf16)hi[2]; a[mg][7] = (bf16)hi[3];
            }
            #pragma unroll
            for (int i = 0; i < 3; ++i) {
                const int nt = wave * 3 + i;
                const bf16x8 wf = *(const bf16x8*)(wb + ss * 6144 + quad * 1536
                                                   + (nt * 16 + l15) * 8);
                #pragma unroll
                for (int mg = 0; mg < 2; ++mg)
                    acc[mg][i] = MFMA16(a[mg], wf, acc[mg][i]);
            }
        }

        pipe_sync();   // drain prefetch (overlapped by compute above), free buf[s&1]
    }

    // epilogue: row t = m0+mg*16+quad*4+r, col n = (wave*3+i)*16+l15
    #pragma unroll
    for (int mg = 0; mg < 2; ++mg)
        #pragma unroll
        for (int i = 0; i < 3; ++i) {
            const int n = (wave * 3 + i) * 16 + l15;
            const int which = n >> 6, col = n & 63;
            #pragma unroll
            for (int r = 0; r < 4; ++r) {
                const int t = m0 + mg * 16 + quad * 4 + r;
                const bf16 v = (bf16)acc[mg][i][r];
                if (which == 0) {
                    qw[(size_t)t * H_SZ + col] = v;
                } else if (which == 1) {
                    // K slab: jt*4096 + ((col>>5)*4 + ((col>>3)&3))*512 + (t&63)*8 + (col&7)
                    kw2[(size_t)(t >> 6) * 4096
                        + (size_t)(((col >> 5) << 2) + ((col >> 3) & 3)) * 512
                        + (size_t)(t & 63) * 8 + (col & 7)] = v;
                } else {
                    // V slab: jt*4096 + ((((t>>5)&1)<<2) + ((t>>3)&3))*512 + col*8 + (t&7)
                    vtw2[(size_t)(t >> 6) * 4096
                         + (size_t)((((t >> 5) & 1) << 2) + ((t >> 3) & 3)) * 512
                         + (size_t)col * 8 + (t & 7)] = v;
                }
            }
        }
}

// -------------------------------------------------------------------------
// K2: causal flash. grid 1024 x 256. Item (b, qt64, h): 64 q-rows, 4 waves
// share each 16KB K/V slab; sweep jt = h, h+4, ...; additive partials to pbuf.
// Double-buffered KV slab: stage jt+4 at top, compute jt, one barrier/iter.
// -------------------------------------------------------------------------
__global__ __launch_bounds__(256) void flash_attn(
    const bf16* __restrict__ qw, const bf16* __restrict__ kw2,
    const bf16* __restrict__ vtw2, float* __restrict__ pbuf)
{
    const int bx = blockIdx.x;
    const int item = (bx & 1) ? (1023 - (bx >> 1)) : (bx >> 1);
    const int qt = 63 - (item >> 4);
    const int b  = (item >> 2) & 3;
    const int h  = item & 3;
    const int i0 = qt * 64;
    const int nkv = qt + 1;

    const int tid = threadIdx.x;
    const int mg = tid >> 6, lane = tid & 63;
    const int quad = lane >> 4, l15 = lane & 15;

    __shared__ __align__(16) bf16 kvs[2][8192];     // 2 x 16 KB: K 8K | V 8K
    __shared__ __align__(16) bf16 pls[4][16 * 72];  // 9.2 KB (per-wave scratch)

    bf16x8 aq0, aq1;
    {
        const bf16* qp = qw + ((size_t)b * T_SZ + i0 + mg * 16 + l15) * H_SZ + quad * 8;
        aq0 = *(const bf16x8*)qp;
        aq1 = *(const bf16x8*)(qp + 32);
    }
    const bf16 onev = (bf16)1.0f;
    const bf16x8 vone = {onev, onev, onev, onev, onev, onev, onev, onev};

    const char* kgb = (const char*)kw2 + (size_t)b * 524288;
    const char* vgb = (const char*)vtw2 + (size_t)b * 524288;
    bf16* pl = pls[mg];

    f32x4 o[4] = {};
    f32x4 osum = {};

    auto stage = [&](int jt, int buf) {
        const char* ks = kgb + (size_t)jt * 8192;
        const char* vs = vgb + (size_t)jt * 8192;
        char* dst = (char*)(&kvs[buf][0]) + (size_t)tid * 16;
        dma16(ks + (size_t)tid * 16, dst);
        dma16(ks + 4096 + (size_t)tid * 16, dst + 4096);
        dma16(vs + (size_t)tid * 16, dst + 8192);
        dma16(vs + 4096 + (size_t)tid * 16, dst + 12288);
    };

    if (h < nkv) {
        stage(h, 0);
        pipe_sync();                               // buf0 ready
    }

    int c = 0;
    for (int jt = h; jt < nkv; jt += 4, c ^= 1) {
        if (jt + 4 < nkv) stage(jt + 4, c ^ 1);    // prefetch next KV slab
        const bf16* kb = &kvs[c][0];
        const bf16* vb = &kvs[c][0] + 4096;

        f32x4 s4[4] = {};
        __builtin_amdgcn_s_setprio(1);
        #pragma unroll
        for (int ct = 0; ct < 4; ++ct) {
            const bf16x8 k0 = *(const bf16x8*)(kb + (0 * 4 + quad) * 512 + (ct * 16 + l15) * 8);
            const bf16x8 k1 = *(const bf16x8*)(kb + (1 * 4 + quad) * 512 + (ct * 16 + l15) * 8);
            s4[ct] = MFMA16(aq0, k0, s4[ct]);
            s4[ct] = MFMA16(aq1, k1, s4[ct]);
        }
        __builtin_amdgcn_s_setprio(0);
        if (jt == qt) {
            #pragma unroll
            for (int ct = 0; ct < 4; ++ct) {
                const int col = ct * 16 + l15;
                const int row = mg * 16 + quad * 4;
                #pragma unroll
                for (int rr = 0; rr < 4; ++rr)
                    if (col > row + rr) s4[ct][rr] = -3.0e38f;
            }
        }
        #pragma unroll
        for (int ct = 0; ct < 4; ++ct)
            #pragma unroll
            for (int rr = 0; rr < 4; ++rr)
                pl[(quad * 4 + rr) * 72 + ct * 16 + l15] = (bf16)EXP2(s4[ct][rr]);
        const bf16x8 pa0 = *(const bf16x8*)&pl[l15 * 72 + quad * 8];
        const bf16x8 pa1 = *(const bf16x8*)&pl[l15 * 72 + 32 + quad * 8];

        __builtin_amdgcn_s_setprio(1);
        #pragma unroll
        for (int ht = 0; ht < 4; ++ht) {
            const bf16x8 v0 = *(const bf16x8*)(vb + (0 * 4 + quad) * 512 + (ht * 16 + l15) * 8);
            const bf16x8 v1 = *(const bf16x8*)(vb + (1 * 4 + quad) * 512 + (ht * 16 + l15) * 8);
            o[ht] = MFMA16(pa0, v0, o[ht]);
            o[ht] = MFMA16(pa1, v1, o[ht]);
        }
        osum = MFMA16(pa0, vone, osum);
        osum = MFMA16(pa1, vone, osum);
        __builtin_amdgcn_s_setprio(0);

        pipe_sync();   // drain prefetch (overlapped by compute), free kvs[c]
    }

    float* pb = pbuf + (size_t)(((b * 64 + qt) * 4) + h) * P_STR;
    #pragma unroll
    for (int ht = 0; ht < 4; ++ht)
        #pragma unroll
        for (int rr = 0; rr < 4; ++rr)
            pb[(mg * 16 + quad * 4 + rr) * 64 + ht * 16 + l15] = o[ht][rr];
    if (l15 == 0) {
        #pragma unroll
        for (int rr = 0; rr < 4; ++rr)
            pb[4096 + mg * 16 + quad * 4 + rr] = osum[rr];
    }
}

// -------------------------------------------------------------------------
// K3: combine. grid 512 x 256. out = sum_h O_h / sum_h l_h. 32 rows/block.
// -------------------------------------------------------------------------
__global__ __launch_bounds__(256) void combine(
    const float* __restrict__ pbuf, float* __restrict__ out)
{
    const int bq = blockIdx.x >> 1, tid = threadIdx.x;
    const int row = ((blockIdx.x & 1) << 5) + (tid >> 3);
    const int c0 = (tid & 7) * 8;
    const float* p = pbuf + (size_t)bq * 4 * P_STR;

    f32x4 a0 = {}, a1 = {};
    float l = 0.f;
    #pragma unroll
    for (int h = 0; h < 4; ++h) {
        const float* ph = p + (size_t)h * P_STR + row * 64 + c0;
        a0 += *(const f32x4*)(ph);
        a1 += *(const f32x4*)(ph + 4);
        l  += p[(size_t)h * P_STR + 4096 + row];
    }
    const float inv = 1.0f / l;
    float* op = out + ((size_t)bq * 64 + row) * 64 + c0;
    *(f32x4*)(op)     = a0 * inv;
    *(f32x4*)(op + 4) = a1 * inv;
}

extern "C" void kernel_launch(void* const* d_in, const int* in_sizes, int n_in,
                              void* d_out, int out_size, void* d_ws, size_t ws_size,
                              hipStream_t stream) {
    const float* x  = (const float*)d_in[0];
    const float* Wq = (const float*)d_in[1];
    const float* Wk = (const float*)d_in[2];
    const float* Wv = (const float*)d_in[3];

    bf16* qw   = (bf16*)d_ws;                          // 2 MB, plain [t][h]
    bf16* kw2  = qw + (size_t)M_SZ * H_SZ;             // 2 MB, per-kv-tile slabs
    bf16* vtw2 = kw2 + (size_t)M_SZ * H_SZ;            // 2 MB, per-kv-tile slabs
    bf16* wt2  = vtw2 + (size_t)M_SZ * H_SZ;           // 384 KB, per-step slabs
    float* pbuf = (float*)(wt2 + 3 * 64 * 1024);       // 17 MB partials
    float* out = (float*)d_out;

    wt_prep<<<48, 256, 0, stream>>>(Wq, Wk, Wv, wt2);
    qkv_proj<<<M_SZ / 32, 256, 0, stream>>>(x, wt2, qw, kw2, vtw2);
    flash_attn<<<1024, 256, 0, stream>>>(qw, kw2, vtw2, pbuf);
    combine<<<512, 256, 0, stream>>>(pbuf, out);
}

// Round 3
// 148.697 us; speedup vs baseline: 1.0233x; 1.0233x over previous
//
#include <hip/hip_runtime.h>
#include <cstdint>

// Head attention: x[4,4096,1024] fp32, Wq/Wk/Wv[1024,64] fp32 -> out[4,4096,64] fp32.
// Round 12: K0/K1 reverted to exact r9 (best measured). K2 rebuilt as fat-tile:
// item (b, qt2, h) = 128 q-rows, 4 waves x 32 rows (2 row-groups/wave) -> each
// K/V LDS fragment feeds 2x MFMAs (LDS-port pressure -40%, the r8 bottleneck).
// K2 keeps dbuf prefetch (2 blocks/CU now) + setprio. K3 adjusted to new pbuf.
//  K0: wt_prep  - W -> bf16 per-64k-step LDS-image slabs; Wq pre-scaled (frozen)
//  K1: qkv_proj - r9 exact: 32-row blocks, BK=64, staggered slab phase
//  K2: flash    - item (b, qt2-128rows, h4): dbuf 16KB KV slab, 32 rows/wave
//  K3: combine  - out = sum_h O_h / sum_h l_h over 128-row partials

typedef __bf16 bf16;
typedef __bf16 bf16x8 __attribute__((ext_vector_type(8)));
typedef float  f32x4  __attribute__((ext_vector_type(4)));

#define MFMA16(a, b, c) __builtin_amdgcn_mfma_f32_16x16x32_bf16((a), (b), (c), 0, 0, 0)

#if __has_builtin(__builtin_amdgcn_exp2f)
#define EXP2(x) __builtin_amdgcn_exp2f(x)
#else
#define EXP2(x) exp2f(x)
#endif

#define B_SZ 4
#define T_SZ 4096
#define C_SZ 1024
#define H_SZ 64
#define M_SZ (B_SZ * T_SZ)
#define QSCALE (1.4426950408889634f / 32.0f)   // log2(e)/sqrt(1024)
#define P_STR 8320                             // floats per partial: 128x64 O + 128 l

// async 16B global->LDS DMA; LDS dest is wave-uniform base + lane*16.
__device__ __forceinline__ void dma16(const void* g, void* l) {
    __builtin_amdgcn_global_load_lds(
        (const __attribute__((address_space(1))) uint32_t*)(uintptr_t)g,
        (__attribute__((address_space(3))) uint32_t*)(uint32_t)(uintptr_t)l,
        16, 0, 0);
}

// bottom-of-iter pipeline sync: drain own prefetch DMAs, sync block, pin sched.
__device__ __forceinline__ void pipe_sync() {
    asm volatile("s_waitcnt vmcnt(0)" ::: "memory");
    __builtin_amdgcn_s_barrier();
    __builtin_amdgcn_sched_barrier(0);
}

// -------------------------------------------------------------------------
// K0: wt2 image, per 64-k outer step s: elem off =
//   s*12288 + sub*6144 + quad*1536 + n*8 + j  (k = s*64+sub*32+quad*8+j, n = 0..191).
// -------------------------------------------------------------------------
__global__ __launch_bounds__(256) void wt_prep(
    const float* __restrict__ Wq, const float* __restrict__ Wk,
    const float* __restrict__ Wv, bf16* __restrict__ wt2)
{
    const int n4 = blockIdx.x, t = threadIdx.x;
    const int nbase = n4 * 4;
    const float* W = (nbase < 64) ? Wq : (nbase < 128 ? Wk : Wv);
    const float sc = (nbase < 64) ? QSCALE : 1.0f;
    const int ncol = nbase & 63;
    #pragma unroll
    for (int i = 0; i < 4; ++i) {
        const int k = i * 256 + t;
        const float4 v = *(const float4*)(W + (size_t)k * H_SZ + ncol);
        const float vals[4] = {v.x, v.y, v.z, v.w};
        const size_t base = (size_t)(k >> 6) * 12288 + (size_t)((k >> 5) & 1) * 6144
                          + (size_t)((k >> 3) & 3) * 1536 + (k & 7);
        #pragma unroll
        for (int m = 0; m < 4; ++m)
            wt2[base + (size_t)(nbase + m) * 8] = (bf16)(vals[m] * sc);
    }
}

// -------------------------------------------------------------------------
// K1: qkv (r9 exact). grid 512 x 256 (4 waves). Block = 32 rows x 192 cols.
// 16 steps of BK=64, slab phase staggered by block. Per step: DMA x slab
// [sub][quad][row32][8f] (8KB) + W slab (24KB); 12 MFMA/wave/step.
// -------------------------------------------------------------------------
__global__ __launch_bounds__(256) void qkv_proj(
    const float* __restrict__ x, const bf16* __restrict__ wt2,
    bf16* __restrict__ qw, bf16* __restrict__ kw2, bf16* __restrict__ vtw2)
{
    const int m0 = blockIdx.x * 32;
    const int tid = threadIdx.x;
    const int wave = tid >> 6, lane = tid & 63;
    const int quad = lane >> 4, l15 = lane & 15;
    const int phase = blockIdx.x & 15;             // slab-phase stagger

    __shared__ __align__(16) float xs[2 * 4 * 32 * 8];   // 8 KB
    __shared__ __align__(16) bf16  ws[2 * 4 * 192 * 8];  // 24 KB

    f32x4 acc[2][3] = {};                          // [mg][ntile]

    // x DMA granule (per thread, i in {0,1}): sub=i, quad=(tid>>6)&3,
    // row=(tid>>1)&31, half=tid&1. k-offset within step: sub*128B+quad*32B+half*16B.
    const char* xg = (const char*)x
        + (size_t)(m0 + ((tid >> 1) & 31)) * 4096
        + (size_t)((tid >> 6) & 3) * 32 + (size_t)(tid & 1) * 16;
    char* xl = (char*)xs + (size_t)tid * 16;
    const char* wg = (const char*)wt2 + (size_t)tid * 16;
    char* wl = (char*)ws + (size_t)tid * 16;

    for (int s = 0; s < 16; ++s) {
        const size_t se = (size_t)((s + phase) & 15);
        __syncthreads();                           // prior step's reads done
        dma16(xg + se * 256, xl);
        dma16(xg + se * 256 + 128, xl + 4096);
        #pragma unroll
        for (int i = 0; i < 6; ++i)
            dma16(wg + se * 24576 + (size_t)i * 4096, wl + (size_t)i * 4096);
        __syncthreads();                           // drain -> slabs visible

        #pragma unroll
        for (int ss = 0; ss < 2; ++ss) {
            bf16x8 a[2];
            #pragma unroll
            for (int mg = 0; mg < 2; ++mg) {
                const float* ap = xs + ss * 1024 + quad * 256 + (mg * 16 + l15) * 8;
                const f32x4 lo = *(const f32x4*)ap;
                const f32x4 hi = *(const f32x4*)(ap + 4);
                a[mg][0] = (bf16)lo[0]; a[mg][1] = (bf16)lo[1];
                a[mg][2] = (bf16)lo[2]; a[mg][3] = (bf16)lo[3];
                a[mg][4] = (bf16)hi[0]; a[mg][5] = (bf16)hi[1];
                a[mg][6] = (bf16)hi[2]; a[mg][7] = (bf16)hi[3];
            }
            #pragma unroll
            for (int i = 0; i < 3; ++i) {
                const int nt = wave * 3 + i;
                const bf16x8 wf = *(const bf16x8*)(ws + ss * 6144 + quad * 1536
                                                   + (nt * 16 + l15) * 8);
                #pragma unroll
                for (int mg = 0; mg < 2; ++mg)
                    acc[mg][i] = MFMA16(a[mg], wf, acc[mg][i]);
            }
        }
    }

    // epilogue: row t = m0+mg*16+quad*4+r, col n = (wave*3+i)*16+l15
    #pragma unroll
    for (int mg = 0; mg < 2; ++mg)
        #pragma unroll
        for (int i = 0; i < 3; ++i) {
            const int n = (wave * 3 + i) * 16 + l15;
            const int which = n >> 6, col = n & 63;
            #pragma unroll
            for (int r = 0; r < 4; ++r) {
                const int t = m0 + mg * 16 + quad * 4 + r;
                const bf16 v = (bf16)acc[mg][i][r];
                if (which == 0) {
                    qw[(size_t)t * H_SZ + col] = v;
                } else if (which == 1) {
                    // K slab: jt*4096 + ((col>>5)*4 + ((col>>3)&3))*512 + (t&63)*8 + (col&7)
                    kw2[(size_t)(t >> 6) * 4096
                        + (size_t)(((col >> 5) << 2) + ((col >> 3) & 3)) * 512
                        + (size_t)(t & 63) * 8 + (col & 7)] = v;
                } else {
                    // V slab: jt*4096 + ((((t>>5)&1)<<2) + ((t>>3)&3))*512 + col*8 + (t&7)
                    vtw2[(size_t)(t >> 6) * 4096
                         + (size_t)((((t >> 5) & 1) << 2) + ((t >> 3) & 3)) * 512
                         + (size_t)col * 8 + (t & 7)] = v;
                }
            }
        }
}

// -------------------------------------------------------------------------
// K2: causal flash, fat tile. grid 512 x 256. Item (b, qt2 in 0..31, h in 0..3):
// 128 q-rows, 4 waves x 32 rows (mg2 = 2 row-groups of 16 per wave).
// Each K/V LDS fragment read once per wave, used for both row-groups.
// Double-buffered 16KB KV slab: stage jt+4 at top, compute jt, 1 barrier/iter.
// Partials (additive exp2, no max): 128x64 O + 128 l per (b,qt2,h) -> pbuf.
// -------------------------------------------------------------------------
__global__ __launch_bounds__(256) void flash_attn(
    const bf16* __restrict__ qw, const bf16* __restrict__ kw2,
    const bf16* __restrict__ vtw2, float* __restrict__ pbuf)
{
    const int bx = blockIdx.x;
    const int item = (bx & 1) ? (511 - (bx >> 1)) : (bx >> 1);  // serpentine
    const int qt2 = 31 - (item >> 4);                           // heavy first
    const int b   = (item >> 2) & 3;
    const int h   = item & 3;
    const int i0  = qt2 * 128;
    const int nkv = qt2 * 2 + 2;     // kv tiles 0..2*qt2+1 cover the 128 q-rows

    const int tid = threadIdx.x;
    const int wave = tid >> 6, lane = tid & 63;
    const int quad = lane >> 4, l15 = lane & 15;

    __shared__ __align__(16) bf16 kvs[2][8192];      // 2 x 16 KB: K 8K | V 8K
    __shared__ __align__(16) bf16 pls[4][32 * 72];   // 18 KB: per-wave P scratch

    // Q frags: rows i0 + wave*32 + mg2*16 + l15, head-dim quad*8 (+32)
    bf16x8 aq[2][2];
    #pragma unroll
    for (int mg2 = 0; mg2 < 2; ++mg2) {
        const bf16* qp = qw + ((size_t)b * T_SZ + i0 + wave * 32 + mg2 * 16 + l15) * H_SZ
                       + quad * 8;
        aq[mg2][0] = *(const bf16x8*)qp;
        aq[mg2][1] = *(const bf16x8*)(qp + 32);
    }
    const bf16 onev = (bf16)1.0f;
    const bf16x8 vone = {onev, onev, onev, onev, onev, onev, onev, onev};

    const char* kgb = (const char*)kw2 + (size_t)b * 524288;
    const char* vgb = (const char*)vtw2 + (size_t)b * 524288;
    bf16* pl = pls[wave];

    f32x4 o[2][4] = {};
    f32x4 osum[2] = {};

    auto stage = [&](int jt, int buf) {
        const char* ks = kgb + (size_t)jt * 8192;
        const char* vs = vgb + (size_t)jt * 8192;
        char* dst = (char*)(&kvs[buf][0]) + (size_t)tid * 16;
        dma16(ks + (size_t)tid * 16, dst);
        dma16(ks + 4096 + (size_t)tid * 16, dst + 4096);
        dma16(vs + (size_t)tid * 16, dst + 8192);
        dma16(vs + 4096 + (size_t)tid * 16, dst + 12288);
    };

    if (h < nkv) {
        stage(h, 0);
        pipe_sync();                               // buf0 ready
    }

    int c = 0;
    for (int jt = h; jt < nkv; jt += 4, c ^= 1) {
        if (jt + 4 < nkv) stage(jt + 4, c ^ 1);    // prefetch next KV slab
        const bf16* kb = &kvs[c][0];
        const bf16* vb = &kvs[c][0] + 4096;

        // QK: each K frag read once, used for both row-groups.
        f32x4 s4[2][4] = {};
        __builtin_amdgcn_s_setprio(1);
        #pragma unroll
        for (int ct = 0; ct < 4; ++ct) {
            const bf16x8 k0 = *(const bf16x8*)(kb + (0 * 4 + quad) * 512 + (ct * 16 + l15) * 8);
            const bf16x8 k1 = *(const bf16x8*)(kb + (1 * 4 + quad) * 512 + (ct * 16 + l15) * 8);
            #pragma unroll
            for (int mg2 = 0; mg2 < 2; ++mg2) {
                s4[mg2][ct] = MFMA16(aq[mg2][0], k0, s4[mg2][ct]);
                s4[mg2][ct] = MFMA16(aq[mg2][1], k1, s4[mg2][ct]);
            }
        }
        __builtin_amdgcn_s_setprio(0);

        // causal mask: only the top two kv tiles can cross the diagonal
        if (jt >= 2 * qt2) {
            #pragma unroll
            for (int mg2 = 0; mg2 < 2; ++mg2) {
                const int grow = i0 + wave * 32 + mg2 * 16 + quad * 4;
                #pragma unroll
                for (int ct = 0; ct < 4; ++ct) {
                    const int gcol = jt * 64 + ct * 16 + l15;
                    #pragma unroll
                    for (int rr = 0; rr < 4; ++rr)
                        if (gcol > grow + rr) s4[mg2][ct][rr] = -3.0e38f;
                }
            }
        }

        // P = exp2(S) -> per-wave LDS scratch (rows mg2*16+quad*4+rr, cols ct*16+l15)
        #pragma unroll
        for (int mg2 = 0; mg2 < 2; ++mg2)
            #pragma unroll
            for (int ct = 0; ct < 4; ++ct)
                #pragma unroll
                for (int rr = 0; rr < 4; ++rr)
                    pl[(mg2 * 16 + quad * 4 + rr) * 72 + ct * 16 + l15]
                        = (bf16)EXP2(s4[mg2][ct][rr]);

        // A-frags for PV: row = mg2*16 + l15, kv = quad*8 (+32)
        bf16x8 pa[2][2];
        #pragma unroll
        for (int mg2 = 0; mg2 < 2; ++mg2) {
            pa[mg2][0] = *(const bf16x8*)&pl[(mg2 * 16 + l15) * 72 + quad * 8];
            pa[mg2][1] = *(const bf16x8*)&pl[(mg2 * 16 + l15) * 72 + 32 + quad * 8];
        }

        // PV: each V frag read once, used for both row-groups.
        __builtin_amdgcn_s_setprio(1);
        #pragma unroll
        for (int ht = 0; ht < 4; ++ht) {
            const bf16x8 v0 = *(const bf16x8*)(vb + (0 * 4 + quad) * 512 + (ht * 16 + l15) * 8);
            const bf16x8 v1 = *(const bf16x8*)(vb + (1 * 4 + quad) * 512 + (ht * 16 + l15) * 8);
            #pragma unroll
            for (int mg2 = 0; mg2 < 2; ++mg2) {
                o[mg2][ht] = MFMA16(pa[mg2][0], v0, o[mg2][ht]);
                o[mg2][ht] = MFMA16(pa[mg2][1], v1, o[mg2][ht]);
            }
        }
        #pragma unroll
        for (int mg2 = 0; mg2 < 2; ++mg2) {
            osum[mg2] = MFMA16(pa[mg2][0], vone, osum[mg2]);
            osum[mg2] = MFMA16(pa[mg2][1], vone, osum[mg2]);
        }
        __builtin_amdgcn_s_setprio(0);

        pipe_sync();   // drain prefetch (overlapped by compute), free kvs[c]
    }

    // epilogue: partial O rows L = wave*32 + mg2*16 + quad*4 + rr
    float* pb = pbuf + (size_t)(((b * 32 + qt2) * 4) + h) * P_STR;
    #pragma unroll
    for (int mg2 = 0; mg2 < 2; ++mg2) {
        const int L0 = wave * 32 + mg2 * 16 + quad * 4;
        #pragma unroll
        for (int ht = 0; ht < 4; ++ht)
            #pragma unroll
            for (int rr = 0; rr < 4; ++rr)
                pb[(L0 + rr) * 64 + ht * 16 + l15] = o[mg2][ht][rr];
        if (l15 == 0) {
            #pragma unroll
            for (int rr = 0; rr < 4; ++rr)
                pb[8192 + L0 + rr] = osum[mg2][rr];
        }
    }
}

// -------------------------------------------------------------------------
// K3: combine. grid 256 x 256. out = sum_h O_h / sum_h l_h.
// Block = 64 rows of one (b,qt2) 128-row partial set (half = bx&1).
// -------------------------------------------------------------------------
__global__ __launch_bounds__(256) void combine(
    const float* __restrict__ pbuf, float* __restrict__ out)
{
    const int bq2 = blockIdx.x >> 1, tid = threadIdx.x;
    const int row = ((blockIdx.x & 1) << 6) + (tid >> 2);   // 0..127
    const int c0 = (tid & 3) * 16;
    const float* p = pbuf + (size_t)bq2 * 4 * P_STR;

    f32x4 a0 = {}, a1 = {}, a2 = {}, a3 = {};
    float l = 0.f;
    #pragma unroll
    for (int h = 0; h < 4; ++h) {
        const float* ph = p + (size_t)h * P_STR + row * 64 + c0;
        a0 += *(const f32x4*)(ph);
        a1 += *(const f32x4*)(ph + 4);
        a2 += *(const f32x4*)(ph + 8);
        a3 += *(const f32x4*)(ph + 12);
        l  += p[(size_t)h * P_STR + 8192 + row];
    }
    const float inv = 1.0f / l;
    float* op = out + ((size_t)bq2 * 128 + row) * 64 + c0;
    *(f32x4*)(op)      = a0 * inv;
    *(f32x4*)(op + 4)  = a1 * inv;
    *(f32x4*)(op + 8)  = a2 * inv;
    *(f32x4*)(op + 12) = a3 * inv;
}

extern "C" void kernel_launch(void* const* d_in, const int* in_sizes, int n_in,
                              void* d_out, int out_size, void* d_ws, size_t ws_size,
                              hipStream_t stream) {
    const float* x  = (const float*)d_in[0];
    const float* Wq = (const float*)d_in[1];
    const float* Wk = (const float*)d_in[2];
    const float* Wv = (const float*)d_in[3];

    bf16* qw   = (bf16*)d_ws;                          // 2 MB, plain [t][h]
    bf16* kw2  = qw + (size_t)M_SZ * H_SZ;             // 2 MB, per-kv-tile slabs
    bf16* vtw2 = kw2 + (size_t)M_SZ * H_SZ;            // 2 MB, per-kv-tile slabs
    bf16* wt2  = vtw2 + (size_t)M_SZ * H_SZ;           // 384 KB, per-step slabs
    float* pbuf = (float*)(wt2 + 3 * 64 * 1024);       // 17 MB partials
    float* out = (float*)d_out;

    wt_prep<<<48, 256, 0, stream>>>(Wq, Wk, Wv, wt2);
    qkv_proj<<<M_SZ / 32, 256, 0, stream>>>(x, wt2, qw, kw2, vtw2);
    flash_attn<<<512, 256, 0, stream>>>(qw, kw2, vtw2, pbuf);
    combine<<<256, 256, 0, stream>>>(pbuf, out);
}

// Round 4
// 143.756 us; speedup vs baseline: 1.0584x; 1.0344x over previous
//
#include <hip/hip_runtime.h>
#include <cstdint>

// Head attention: x[4,4096,1024] fp32, Wq/Wk/Wv[1024,64] fp32 -> out[4,4096,64] fp32.
// Round 13 (on r12): two independent cost cuts.
//  (a) K2 P-store: kv-permuted P scratch (col' = l15*4+ct) -> 8 ds_write_b64
//      instead of 32 ds_write_b16 per wave-visit; vtw2 built with the SAME kv
//      permutation (p = (t&15)*4 + (t>>4) per 64-tile) so PV k-order matches.
//  (b) O-partials stored bf16 (pbuf_o) + l partials f32 (pbuf_l): pbuf
//      round-trip 34 MB -> ~17 MB.
//  K0: wt_prep  - W -> bf16 per-64k-step LDS-image slabs; Wq pre-scaled (frozen)
//  K1: qkv_proj - r9 exact + vtw2 kv-permutation in epilogue
//  K2: flash    - fat tile (b, qt2-128rows, h4), dbuf 16KB KV slab, b64 P-writes
//  K3: combine  - out = sum_h O_h / sum_h l_h over bf16 partials

typedef __bf16 bf16;
typedef __bf16 bf16x4 __attribute__((ext_vector_type(4)));
typedef __bf16 bf16x8 __attribute__((ext_vector_type(8)));
typedef float  f32x4  __attribute__((ext_vector_type(4)));

#define MFMA16(a, b, c) __builtin_amdgcn_mfma_f32_16x16x32_bf16((a), (b), (c), 0, 0, 0)

#if __has_builtin(__builtin_amdgcn_exp2f)
#define EXP2(x) __builtin_amdgcn_exp2f(x)
#else
#define EXP2(x) exp2f(x)
#endif

#define B_SZ 4
#define T_SZ 4096
#define C_SZ 1024
#define H_SZ 64
#define M_SZ (B_SZ * T_SZ)
#define QSCALE (1.4426950408889634f / 32.0f)   // log2(e)/sqrt(1024)
#define P_O 8192                               // bf16 elems per O-partial (128x64)
#define P_L 128                                // f32 elems per l-partial

// async 16B global->LDS DMA; LDS dest is wave-uniform base + lane*16.
__device__ __forceinline__ void dma16(const void* g, void* l) {
    __builtin_amdgcn_global_load_lds(
        (const __attribute__((address_space(1))) uint32_t*)(uintptr_t)g,
        (__attribute__((address_space(3))) uint32_t*)(uint32_t)(uintptr_t)l,
        16, 0, 0);
}

// bottom-of-iter pipeline sync: drain own prefetch DMAs, sync block, pin sched.
__device__ __forceinline__ void pipe_sync() {
    asm volatile("s_waitcnt vmcnt(0)" ::: "memory");
    __builtin_amdgcn_s_barrier();
    __builtin_amdgcn_sched_barrier(0);
}

// -------------------------------------------------------------------------
// K0: wt2 image, per 64-k outer step s: elem off =
//   s*12288 + sub*6144 + quad*1536 + n*8 + j  (k = s*64+sub*32+quad*8+j, n = 0..191).
// -------------------------------------------------------------------------
__global__ __launch_bounds__(256) void wt_prep(
    const float* __restrict__ Wq, const float* __restrict__ Wk,
    const float* __restrict__ Wv, bf16* __restrict__ wt2)
{
    const int n4 = blockIdx.x, t = threadIdx.x;
    const int nbase = n4 * 4;
    const float* W = (nbase < 64) ? Wq : (nbase < 128 ? Wk : Wv);
    const float sc = (nbase < 64) ? QSCALE : 1.0f;
    const int ncol = nbase & 63;
    #pragma unroll
    for (int i = 0; i < 4; ++i) {
        const int k = i * 256 + t;
        const float4 v = *(const float4*)(W + (size_t)k * H_SZ + ncol);
        const float vals[4] = {v.x, v.y, v.z, v.w};
        const size_t base = (size_t)(k >> 6) * 12288 + (size_t)((k >> 5) & 1) * 6144
                          + (size_t)((k >> 3) & 3) * 1536 + (k & 7);
        #pragma unroll
        for (int m = 0; m < 4; ++m)
            wt2[base + (size_t)(nbase + m) * 8] = (bf16)(vals[m] * sc);
    }
}

// -------------------------------------------------------------------------
// K1: qkv (r9 core). grid 512 x 256 (4 waves). Block = 32 rows x 192 cols.
// 16 steps of BK=64, slab phase staggered by block. Per step: DMA x slab
// [sub][quad][row32][8f] (8KB) + W slab (24KB); 12 MFMA/wave/step.
// vtw2 epilogue uses kv-permutation p = (t6&15)*4 + (t6>>4) per 64-tile.
// -------------------------------------------------------------------------
__global__ __launch_bounds__(256) void qkv_proj(
    const float* __restrict__ x, const bf16* __restrict__ wt2,
    bf16* __restrict__ qw, bf16* __restrict__ kw2, bf16* __restrict__ vtw2)
{
    const int m0 = blockIdx.x * 32;
    const int tid = threadIdx.x;
    const int wave = tid >> 6, lane = tid & 63;
    const int quad = lane >> 4, l15 = lane & 15;
    const int phase = blockIdx.x & 15;             // slab-phase stagger

    __shared__ __align__(16) float xs[2 * 4 * 32 * 8];   // 8 KB
    __shared__ __align__(16) bf16  ws[2 * 4 * 192 * 8];  // 24 KB

    f32x4 acc[2][3] = {};                          // [mg][ntile]

    // x DMA granule (per thread, i in {0,1}): sub=i, quad=(tid>>6)&3,
    // row=(tid>>1)&31, half=tid&1. k-offset within step: sub*128B+quad*32B+half*16B.
    const char* xg = (const char*)x
        + (size_t)(m0 + ((tid >> 1) & 31)) * 4096
        + (size_t)((tid >> 6) & 3) * 32 + (size_t)(tid & 1) * 16;
    char* xl = (char*)xs + (size_t)tid * 16;
    const char* wg = (const char*)wt2 + (size_t)tid * 16;
    char* wl = (char*)ws + (size_t)tid * 16;

    for (int s = 0; s < 16; ++s) {
        const size_t se = (size_t)((s + phase) & 15);
        __syncthreads();                           // prior step's reads done
        dma16(xg + se * 256, xl);
        dma16(xg + se * 256 + 128, xl + 4096);
        #pragma unroll
        for (int i = 0; i < 6; ++i)
            dma16(wg + se * 24576 + (size_t)i * 4096, wl + (size_t)i * 4096);
        __syncthreads();                           // drain -> slabs visible

        #pragma unroll
        for (int ss = 0; ss < 2; ++ss) {
            bf16x8 a[2];
            #pragma unroll
            for (int mg = 0; mg < 2; ++mg) {
                const float* ap = xs + ss * 1024 + quad * 256 + (mg * 16 + l15) * 8;
                const f32x4 lo = *(const f32x4*)ap;
                const f32x4 hi = *(const f32x4*)(ap + 4);
                a[mg][0] = (bf16)lo[0]; a[mg][1] = (bf16)lo[1];
                a[mg][2] = (bf16)lo[2]; a[mg][3] = (bf16)lo[3];
                a[mg][4] = (bf16)hi[0]; a[mg][5] = (bf16)hi[1];
                a[mg][6] = (bf16)hi[2]; a[mg][7] = (bf16)hi[3];
            }
            #pragma unroll
            for (int i = 0; i < 3; ++i) {
                const int nt = wave * 3 + i;
                const bf16x8 wf = *(const bf16x8*)(ws + ss * 6144 + quad * 1536
                                                   + (nt * 16 + l15) * 8);
                #pragma unroll
                for (int mg = 0; mg < 2; ++mg)
                    acc[mg][i] = MFMA16(a[mg], wf, acc[mg][i]);
            }
        }
    }

    // epilogue: row t = m0+mg*16+quad*4+r, col n = (wave*3+i)*16+l15
    #pragma unroll
    for (int mg = 0; mg < 2; ++mg)
        #pragma unroll
        for (int i = 0; i < 3; ++i) {
            const int n = (wave * 3 + i) * 16 + l15;
            const int which = n >> 6, col = n & 63;
            #pragma unroll
            for (int r = 0; r < 4; ++r) {
                const int t = m0 + mg * 16 + quad * 4 + r;
                const bf16 v = (bf16)acc[mg][i][r];
                if (which == 0) {
                    qw[(size_t)t * H_SZ + col] = v;
                } else if (which == 1) {
                    // K slab: jt*4096 + ((col>>5)*4 + ((col>>3)&3))*512 + (t&63)*8 + (col&7)
                    kw2[(size_t)(t >> 6) * 4096
                        + (size_t)(((col >> 5) << 2) + ((col >> 3) & 3)) * 512
                        + (size_t)(t & 63) * 8 + (col & 7)] = v;
                } else {
                    // V slab, kv-permuted: t6 = t&63, p = (t6&15)*4 + (t6>>4)
                    // idx = jt*4096 + (p>>3)*512 + col*8 + (p&7)
                    const int t6 = t & 63;
                    const int p = ((t6 & 15) << 2) | (t6 >> 4);
                    vtw2[(size_t)(t >> 6) * 4096
                         + (size_t)(p >> 3) * 512 + (size_t)col * 8 + (p & 7)] = v;
                }
            }
        }
}

// -------------------------------------------------------------------------
// K2: causal flash, fat tile. grid 512 x 256. Item (b, qt2 in 0..31, h in 0..3):
// 128 q-rows, 4 waves x 32 rows (mg2 = 2 row-groups of 16 per wave).
// P scratch layout kv-permuted: element (row, kv) stored at col' = (kv&15)*4
// + (kv>>4), so each thread writes 4 ct values as one ds_write_b64; vtw2's kv
// permutation makes the PV k-order consistent. Double-buffered 16KB KV slab.
// Partials: O bf16 (128x64) -> pbuf_o, l f32 (128) -> pbuf_l.
// -------------------------------------------------------------------------
__global__ __launch_bounds__(256) void flash_attn(
    const bf16* __restrict__ qw, const bf16* __restrict__ kw2,
    const bf16* __restrict__ vtw2, bf16* __restrict__ pbuf_o,
    float* __restrict__ pbuf_l)
{
    const int bx = blockIdx.x;
    const int item = (bx & 1) ? (511 - (bx >> 1)) : (bx >> 1);  // serpentine
    const int qt2 = 31 - (item >> 4);                           // heavy first
    const int b   = (item >> 2) & 3;
    const int h   = item & 3;
    const int i0  = qt2 * 128;
    const int nkv = qt2 * 2 + 2;     // kv tiles 0..2*qt2+1 cover the 128 q-rows

    const int tid = threadIdx.x;
    const int wave = tid >> 6, lane = tid & 63;
    const int quad = lane >> 4, l15 = lane & 15;

    __shared__ __align__(16) bf16 kvs[2][8192];      // 2 x 16 KB: K 8K | V 8K
    __shared__ __align__(16) bf16 pls[4][32 * 72];   // 18 KB: per-wave P scratch

    // Q frags: rows i0 + wave*32 + mg2*16 + l15, head-dim quad*8 (+32)
    bf16x8 aq[2][2];
    #pragma unroll
    for (int mg2 = 0; mg2 < 2; ++mg2) {
        const bf16* qp = qw + ((size_t)b * T_SZ + i0 + wave * 32 + mg2 * 16 + l15) * H_SZ
                       + quad * 8;
        aq[mg2][0] = *(const bf16x8*)qp;
        aq[mg2][1] = *(const bf16x8*)(qp + 32);
    }
    const bf16 onev = (bf16)1.0f;
    const bf16x8 vone = {onev, onev, onev, onev, onev, onev, onev, onev};

    const char* kgb = (const char*)kw2 + (size_t)b * 524288;
    const char* vgb = (const char*)vtw2 + (size_t)b * 524288;
    bf16* pl = pls[wave];

    f32x4 o[2][4] = {};
    f32x4 osum[2] = {};

    auto stage = [&](int jt, int buf) {
        const char* ks = kgb + (size_t)jt * 8192;
        const char* vs = vgb + (size_t)jt * 8192;
        char* dst = (char*)(&kvs[buf][0]) + (size_t)tid * 16;
        dma16(ks + (size_t)tid * 16, dst);
        dma16(ks + 4096 + (size_t)tid * 16, dst + 4096);
        dma16(vs + (size_t)tid * 16, dst + 8192);
        dma16(vs + 4096 + (size_t)tid * 16, dst + 12288);
    };

    if (h < nkv) {
        stage(h, 0);
        pipe_sync();                               // buf0 ready
    }

    int c = 0;
    for (int jt = h; jt < nkv; jt += 4, c ^= 1) {
        if (jt + 4 < nkv) stage(jt + 4, c ^ 1);    // prefetch next KV slab
        const bf16* kb = &kvs[c][0];
        const bf16* vb = &kvs[c][0] + 4096;

        // QK: each K frag read once, used for both row-groups.
        f32x4 s4[2][4] = {};
        __builtin_amdgcn_s_setprio(1);
        #pragma unroll
        for (int ct = 0; ct < 4; ++ct) {
            const bf16x8 k0 = *(const bf16x8*)(kb + (0 * 4 + quad) * 512 + (ct * 16 + l15) * 8);
            const bf16x8 k1 = *(const bf16x8*)(kb + (1 * 4 + quad) * 512 + (ct * 16 + l15) * 8);
            #pragma unroll
            for (int mg2 = 0; mg2 < 2; ++mg2) {
                s4[mg2][ct] = MFMA16(aq[mg2][0], k0, s4[mg2][ct]);
                s4[mg2][ct] = MFMA16(aq[mg2][1], k1, s4[mg2][ct]);
            }
        }
        __builtin_amdgcn_s_setprio(0);

        // causal mask: only the top two kv tiles can cross the diagonal
        if (jt >= 2 * qt2) {
            #pragma unroll
            for (int mg2 = 0; mg2 < 2; ++mg2) {
                const int grow = i0 + wave * 32 + mg2 * 16 + quad * 4;
                #pragma unroll
                for (int ct = 0; ct < 4; ++ct) {
                    const int gcol = jt * 64 + ct * 16 + l15;
                    #pragma unroll
                    for (int rr = 0; rr < 4; ++rr)
                        if (gcol > grow + rr) s4[mg2][ct][rr] = -3.0e38f;
                }
            }
        }

        // P = exp2(S) -> per-wave LDS scratch, kv-permuted columns:
        // element (row = mg2*16+quad*4+rr, col' = l15*4 + ct); one b64/row.
        #pragma unroll
        for (int mg2 = 0; mg2 < 2; ++mg2)
            #pragma unroll
            for (int rr = 0; rr < 4; ++rr) {
                bf16x4 pk;
                pk[0] = (bf16)EXP2(s4[mg2][0][rr]);
                pk[1] = (bf16)EXP2(s4[mg2][1][rr]);
                pk[2] = (bf16)EXP2(s4[mg2][2][rr]);
                pk[3] = (bf16)EXP2(s4[mg2][3][rr]);
                *(bf16x4*)&pl[(mg2 * 16 + quad * 4 + rr) * 72 + l15 * 4] = pk;
            }

        // A-frags for PV: row = mg2*16 + l15, permuted kv window quad*8 (+32)
        bf16x8 pa[2][2];
        #pragma unroll
        for (int mg2 = 0; mg2 < 2; ++mg2) {
            pa[mg2][0] = *(const bf16x8*)&pl[(mg2 * 16 + l15) * 72 + quad * 8];
            pa[mg2][1] = *(const bf16x8*)&pl[(mg2 * 16 + l15) * 72 + 32 + quad * 8];
        }

        // PV: each V frag read once, used for both row-groups.
        __builtin_amdgcn_s_setprio(1);
        #pragma unroll
        for (int ht = 0; ht < 4; ++ht) {
            const bf16x8 v0 = *(const bf16x8*)(vb + (0 * 4 + quad) * 512 + (ht * 16 + l15) * 8);
            const bf16x8 v1 = *(const bf16x8*)(vb + (1 * 4 + quad) * 512 + (ht * 16 + l15) * 8);
            #pragma unroll
            for (int mg2 = 0; mg2 < 2; ++mg2) {
                o[mg2][ht] = MFMA16(pa[mg2][0], v0, o[mg2][ht]);
                o[mg2][ht] = MFMA16(pa[mg2][1], v1, o[mg2][ht]);
            }
        }
        #pragma unroll
        for (int mg2 = 0; mg2 < 2; ++mg2) {
            osum[mg2] = MFMA16(pa[mg2][0], vone, osum[mg2]);
            osum[mg2] = MFMA16(pa[mg2][1], vone, osum[mg2]);
        }
        __builtin_amdgcn_s_setprio(0);

        pipe_sync();   // drain prefetch (overlapped by compute), free kvs[c]
    }

    // epilogue: partial O rows L = wave*32 + mg2*16 + quad*4 + rr (O as bf16)
    bf16* pb_o = pbuf_o + (size_t)(((b * 32 + qt2) * 4) + h) * P_O;
    float* pb_l = pbuf_l + (size_t)(((b * 32 + qt2) * 4) + h) * P_L;
    #pragma unroll
    for (int mg2 = 0; mg2 < 2; ++mg2) {
        const int L0 = wave * 32 + mg2 * 16 + quad * 4;
        #pragma unroll
        for (int ht = 0; ht < 4; ++ht)
            #pragma unroll
            for (int rr = 0; rr < 4; ++rr)
                pb_o[(L0 + rr) * 64 + ht * 16 + l15] = (bf16)o[mg2][ht][rr];
        if (l15 == 0) {
            #pragma unroll
            for (int rr = 0; rr < 4; ++rr)
                pb_l[L0 + rr] = osum[mg2][rr];
        }
    }
}

// -------------------------------------------------------------------------
// K3: combine. grid 256 x 256. out = sum_h O_h / sum_h l_h.
// Block = 64 rows of one (b,qt2) 128-row partial set (half = bx&1).
// -------------------------------------------------------------------------
__global__ __launch_bounds__(256) void combine(
    const bf16* __restrict__ pbuf_o, const float* __restrict__ pbuf_l,
    float* __restrict__ out)
{
    const int bq2 = blockIdx.x >> 1, tid = threadIdx.x;
    const int row = ((blockIdx.x & 1) << 6) + (tid >> 2);   // 0..127
    const int c0 = (tid & 3) * 16;

    float a[16] = {};
    float l = 0.f;
    #pragma unroll
    for (int h = 0; h < 4; ++h) {
        const bf16* ph = pbuf_o + (size_t)(bq2 * 4 + h) * P_O + row * 64 + c0;
        const bf16x8 v0 = *(const bf16x8*)ph;
        const bf16x8 v1 = *(const bf16x8*)(ph + 8);
        #pragma unroll
        for (int j = 0; j < 8; ++j) {
            a[j]     += (float)v0[j];
            a[8 + j] += (float)v1[j];
        }
        l += pbuf_l[(size_t)(bq2 * 4 + h) * P_L + row];
    }
    const float inv = 1.0f / l;
    float* op = out + ((size_t)bq2 * 128 + row) * 64 + c0;
    #pragma unroll
    for (int g = 0; g < 4; ++g) {
        f32x4 v = {a[g * 4], a[g * 4 + 1], a[g * 4 + 2], a[g * 4 + 3]};
        *(f32x4*)(op + g * 4) = v * inv;
    }
}

extern "C" void kernel_launch(void* const* d_in, const int* in_sizes, int n_in,
                              void* d_out, int out_size, void* d_ws, size_t ws_size,
                              hipStream_t stream) {
    const float* x  = (const float*)d_in[0];
    const float* Wq = (const float*)d_in[1];
    const float* Wk = (const float*)d_in[2];
    const float* Wv = (const float*)d_in[3];

    bf16* qw   = (bf16*)d_ws;                          // 2 MB, plain [t][h]
    bf16* kw2  = qw + (size_t)M_SZ * H_SZ;             // 2 MB, per-kv-tile slabs
    bf16* vtw2 = kw2 + (size_t)M_SZ * H_SZ;            // 2 MB, kv-permuted slabs
    bf16* wt2  = vtw2 + (size_t)M_SZ * H_SZ;           // 384 KB, per-step slabs
    bf16* pbuf_o = wt2 + 3 * 64 * 1024;                // 8 MB bf16 O partials
    float* pbuf_l = (float*)(pbuf_o + (size_t)512 * P_O);  // 256 KB l partials
    float* out = (float*)d_out;

    wt_prep<<<48, 256, 0, stream>>>(Wq, Wk, Wv, wt2);
    qkv_proj<<<M_SZ / 32, 256, 0, stream>>>(x, wt2, qw, kw2, vtw2);
    flash_attn<<<512, 256, 0, stream>>>(qw, kw2, vtw2, pbuf_o, pbuf_l);
    combine<<<256, 256, 0, stream>>>(pbuf_o, pbuf_l, out);
}

// Round 5
// 142.597 us; speedup vs baseline: 1.0670x; 1.0081x over previous
//
#include <hip/hip_runtime.h>
#include <cstdint>

// Head attention: x[4,4096,1024] fp32, Wq/Wk/Wv[1024,64] fp32 -> out[4,4096,64] fp32.
// Round 14 (on r13): K2 P stays fully in registers (swapped QK^T).
//  QK computed as MFMA16(K, Q) -> C has kv on rows, q on cols; with the vtw2
//  kv-permutation p(t6) = ((t6>>2)&3)*8 + (t6&3)*2 + ((t6>>4)&1) + (t6>>5)*32,
//  each lane's s4t regs ARE its PV A-fragment (pa[frag][j] =
//  exp2(s4t[(j&1)+2*frag][mg2][j>>1])) -- no LDS P round-trip, pls deleted
//  (K2 LDS 50->32 KB, LDS traffic/wave-iter 24->16 KB).
//  K0: wt_prep  - W -> bf16 per-64k-step LDS-image slabs; Wq pre-scaled (frozen)
//  K1: qkv_proj - r9 core; vtw2 epilogue uses the new kv-permutation
//  K2: flash    - fat tile (b, qt2-128rows, h4), dbuf 16KB KV slab, in-reg P
//  K3: combine  - out = sum_h O_h / sum_h l_h over bf16 partials

typedef __bf16 bf16;
typedef __bf16 bf16x4 __attribute__((ext_vector_type(4)));
typedef __bf16 bf16x8 __attribute__((ext_vector_type(8)));
typedef float  f32x4  __attribute__((ext_vector_type(4)));

#define MFMA16(a, b, c) __builtin_amdgcn_mfma_f32_16x16x32_bf16((a), (b), (c), 0, 0, 0)

#if __has_builtin(__builtin_amdgcn_exp2f)
#define EXP2(x) __builtin_amdgcn_exp2f(x)
#else
#define EXP2(x) exp2f(x)
#endif

#define B_SZ 4
#define T_SZ 4096
#define C_SZ 1024
#define H_SZ 64
#define M_SZ (B_SZ * T_SZ)
#define QSCALE (1.4426950408889634f / 32.0f)   // log2(e)/sqrt(1024)
#define P_O 8192                               // bf16 elems per O-partial (128x64)
#define P_L 128                                // f32 elems per l-partial

// async 16B global->LDS DMA; LDS dest is wave-uniform base + lane*16.
__device__ __forceinline__ void dma16(const void* g, void* l) {
    __builtin_amdgcn_global_load_lds(
        (const __attribute__((address_space(1))) uint32_t*)(uintptr_t)g,
        (__attribute__((address_space(3))) uint32_t*)(uint32_t)(uintptr_t)l,
        16, 0, 0);
}

// bottom-of-iter pipeline sync: drain own prefetch DMAs, sync block, pin sched.
__device__ __forceinline__ void pipe_sync() {
    asm volatile("s_waitcnt vmcnt(0)" ::: "memory");
    __builtin_amdgcn_s_barrier();
    __builtin_amdgcn_sched_barrier(0);
}

// -------------------------------------------------------------------------
// K0: wt2 image, per 64-k outer step s: elem off =
//   s*12288 + sub*6144 + quad*1536 + n*8 + j  (k = s*64+sub*32+quad*8+j, n = 0..191).
// -------------------------------------------------------------------------
__global__ __launch_bounds__(256) void wt_prep(
    const float* __restrict__ Wq, const float* __restrict__ Wk,
    const float* __restrict__ Wv, bf16* __restrict__ wt2)
{
    const int n4 = blockIdx.x, t = threadIdx.x;
    const int nbase = n4 * 4;
    const float* W = (nbase < 64) ? Wq : (nbase < 128 ? Wk : Wv);
    const float sc = (nbase < 64) ? QSCALE : 1.0f;
    const int ncol = nbase & 63;
    #pragma unroll
    for (int i = 0; i < 4; ++i) {
        const int k = i * 256 + t;
        const float4 v = *(const float4*)(W + (size_t)k * H_SZ + ncol);
        const float vals[4] = {v.x, v.y, v.z, v.w};
        const size_t base = (size_t)(k >> 6) * 12288 + (size_t)((k >> 5) & 1) * 6144
                          + (size_t)((k >> 3) & 3) * 1536 + (k & 7);
        #pragma unroll
        for (int m = 0; m < 4; ++m)
            wt2[base + (size_t)(nbase + m) * 8] = (bf16)(vals[m] * sc);
    }
}

// -------------------------------------------------------------------------
// K1: qkv (r9 core). grid 512 x 256 (4 waves). Block = 32 rows x 192 cols.
// 16 steps of BK=64, slab phase staggered by block. Per step: DMA x slab
// [sub][quad][row32][8f] (8KB) + W slab (24KB); 12 MFMA/wave/step.
// vtw2 epilogue: kv-permutation p = ((t6>>2)&3)*8+(t6&3)*2+((t6>>4)&1)+(t6>>5)*32.
// -------------------------------------------------------------------------
__global__ __launch_bounds__(256) void qkv_proj(
    const float* __restrict__ x, const bf16* __restrict__ wt2,
    bf16* __restrict__ qw, bf16* __restrict__ kw2, bf16* __restrict__ vtw2)
{
    const int m0 = blockIdx.x * 32;
    const int tid = threadIdx.x;
    const int wave = tid >> 6, lane = tid & 63;
    const int quad = lane >> 4, l15 = lane & 15;
    const int phase = blockIdx.x & 15;             // slab-phase stagger

    __shared__ __align__(16) float xs[2 * 4 * 32 * 8];   // 8 KB
    __shared__ __align__(16) bf16  ws[2 * 4 * 192 * 8];  // 24 KB

    f32x4 acc[2][3] = {};                          // [mg][ntile]

    // x DMA granule (per thread, i in {0,1}): sub=i, quad=(tid>>6)&3,
    // row=(tid>>1)&31, half=tid&1. k-offset within step: sub*128B+quad*32B+half*16B.
    const char* xg = (const char*)x
        + (size_t)(m0 + ((tid >> 1) & 31)) * 4096
        + (size_t)((tid >> 6) & 3) * 32 + (size_t)(tid & 1) * 16;
    char* xl = (char*)xs + (size_t)tid * 16;
    const char* wg = (const char*)wt2 + (size_t)tid * 16;
    char* wl = (char*)ws + (size_t)tid * 16;

    for (int s = 0; s < 16; ++s) {
        const size_t se = (size_t)((s + phase) & 15);
        __syncthreads();                           // prior step's reads done
        dma16(xg + se * 256, xl);
        dma16(xg + se * 256 + 128, xl + 4096);
        #pragma unroll
        for (int i = 0; i < 6; ++i)
            dma16(wg + se * 24576 + (size_t)i * 4096, wl + (size_t)i * 4096);
        __syncthreads();                           // drain -> slabs visible

        #pragma unroll
        for (int ss = 0; ss < 2; ++ss) {
            bf16x8 a[2];
            #pragma unroll
            for (int mg = 0; mg < 2; ++mg) {
                const float* ap = xs + ss * 1024 + quad * 256 + (mg * 16 + l15) * 8;
                const f32x4 lo = *(const f32x4*)ap;
                const f32x4 hi = *(const f32x4*)(ap + 4);
                a[mg][0] = (bf16)lo[0]; a[mg][1] = (bf16)lo[1];
                a[mg][2] = (bf16)lo[2]; a[mg][3] = (bf16)lo[3];
                a[mg][4] = (bf16)hi[0]; a[mg][5] = (bf16)hi[1];
                a[mg][6] = (bf16)hi[2]; a[mg][7] = (bf16)hi[3];
            }
            #pragma unroll
            for (int i = 0; i < 3; ++i) {
                const int nt = wave * 3 + i;
                const bf16x8 wf = *(const bf16x8*)(ws + ss * 6144 + quad * 1536
                                                   + (nt * 16 + l15) * 8);
                #pragma unroll
                for (int mg = 0; mg < 2; ++mg)
                    acc[mg][i] = MFMA16(a[mg], wf, acc[mg][i]);
            }
        }
    }

    // epilogue: row t = m0+mg*16+quad*4+r, col n = (wave*3+i)*16+l15
    #pragma unroll
    for (int mg = 0; mg < 2; ++mg)
        #pragma unroll
        for (int i = 0; i < 3; ++i) {
            const int n = (wave * 3 + i) * 16 + l15;
            const int which = n >> 6, col = n & 63;
            #pragma unroll
            for (int r = 0; r < 4; ++r) {
                const int t = m0 + mg * 16 + quad * 4 + r;
                const bf16 v = (bf16)acc[mg][i][r];
                if (which == 0) {
                    qw[(size_t)t * H_SZ + col] = v;
                } else if (which == 1) {
                    // K slab: jt*4096 + ((col>>5)*4 + ((col>>3)&3))*512 + (t&63)*8 + (col&7)
                    kw2[(size_t)(t >> 6) * 4096
                        + (size_t)(((col >> 5) << 2) + ((col >> 3) & 3)) * 512
                        + (size_t)(t & 63) * 8 + (col & 7)] = v;
                } else {
                    // V slab, kv-permuted for in-register P:
                    // p = ((t6>>2)&3)*8 + (t6&3)*2 + ((t6>>4)&1) + (t6>>5)*32
                    const int t6 = t & 63;
                    const int p = ((t6 >> 2) & 3) * 8 + (t6 & 3) * 2
                                + ((t6 >> 4) & 1) + (t6 >> 5) * 32;
                    vtw2[(size_t)(t >> 6) * 4096
                         + (size_t)(p >> 3) * 512 + (size_t)col * 8 + (p & 7)] = v;
                }
            }
        }
}

// -------------------------------------------------------------------------
// K2: causal flash, fat tile, in-register P. grid 512 x 256.
// Item (b, qt2 in 0..31, h in 0..3): 128 q-rows, 4 waves x 32 rows.
// QK swapped: s4t[ct][mg2] = MFMA16(K, Q) -> lane (quad,l15) holds
// P^T elems q = mg2*16+l15, kv = ct*16+quad*4+rr. With vtw2's kv-perm,
// pa[mg2][frag][j] = exp2(s4t[(j&1)+2*frag][mg2][j>>1]) -- no LDS for P.
// Double-buffered 16KB KV slab (LDS 32 KB total).
// Partials: O bf16 (128x64) -> pbuf_o, l f32 (128) -> pbuf_l.
// -------------------------------------------------------------------------
__global__ __launch_bounds__(256) void flash_attn(
    const bf16* __restrict__ qw, const bf16* __restrict__ kw2,
    const bf16* __restrict__ vtw2, bf16* __restrict__ pbuf_o,
    float* __restrict__ pbuf_l)
{
    const int bx = blockIdx.x;
    const int item = (bx & 1) ? (511 - (bx >> 1)) : (bx >> 1);  // serpentine
    const int qt2 = 31 - (item >> 4);                           // heavy first
    const int b   = (item >> 2) & 3;
    const int h   = item & 3;
    const int i0  = qt2 * 128;
    const int nkv = qt2 * 2 + 2;     // kv tiles 0..2*qt2+1 cover the 128 q-rows

    const int tid = threadIdx.x;
    const int wave = tid >> 6, lane = tid & 63;
    const int quad = lane >> 4, l15 = lane & 15;

    __shared__ __align__(16) bf16 kvs[2][8192];      // 2 x 16 KB: K 8K | V 8K

    // Q frags (B-operand role): rows i0 + wave*32 + mg2*16 + l15, head quad*8 (+32)
    bf16x8 aq[2][2];
    #pragma unroll
    for (int mg2 = 0; mg2 < 2; ++mg2) {
        const bf16* qp = qw + ((size_t)b * T_SZ + i0 + wave * 32 + mg2 * 16 + l15) * H_SZ
                       + quad * 8;
        aq[mg2][0] = *(const bf16x8*)qp;
        aq[mg2][1] = *(const bf16x8*)(qp + 32);
    }
    const bf16 onev = (bf16)1.0f;
    const bf16x8 vone = {onev, onev, onev, onev, onev, onev, onev, onev};

    const char* kgb = (const char*)kw2 + (size_t)b * 524288;
    const char* vgb = (const char*)vtw2 + (size_t)b * 524288;

    f32x4 o[2][4] = {};
    f32x4 osum[2] = {};

    auto stage = [&](int jt, int buf) {
        const char* ks = kgb + (size_t)jt * 8192;
        const char* vs = vgb + (size_t)jt * 8192;
        char* dst = (char*)(&kvs[buf][0]) + (size_t)tid * 16;
        dma16(ks + (size_t)tid * 16, dst);
        dma16(ks + 4096 + (size_t)tid * 16, dst + 4096);
        dma16(vs + (size_t)tid * 16, dst + 8192);
        dma16(vs + 4096 + (size_t)tid * 16, dst + 12288);
    };

    if (h < nkv) {
        stage(h, 0);
        pipe_sync();                               // buf0 ready
    }

    int c = 0;
    for (int jt = h; jt < nkv; jt += 4, c ^= 1) {
        if (jt + 4 < nkv) stage(jt + 4, c ^ 1);    // prefetch next KV slab
        const bf16* kb = &kvs[c][0];
        const bf16* vb = &kvs[c][0] + 4096;

        // QK swapped: A = K-frag (rows = kv), B = Q-frag (cols = q).
        f32x4 s4t[4][2] = {};                      // [ct][mg2]
        __builtin_amdgcn_s_setprio(1);
        #pragma unroll
        for (int ct = 0; ct < 4; ++ct) {
            const bf16x8 k0 = *(const bf16x8*)(kb + (0 * 4 + quad) * 512 + (ct * 16 + l15) * 8);
            const bf16x8 k1 = *(const bf16x8*)(kb + (1 * 4 + quad) * 512 + (ct * 16 + l15) * 8);
            #pragma unroll
            for (int mg2 = 0; mg2 < 2; ++mg2) {
                s4t[ct][mg2] = MFMA16(k0, aq[mg2][0], s4t[ct][mg2]);
                s4t[ct][mg2] = MFMA16(k1, aq[mg2][1], s4t[ct][mg2]);
            }
        }
        __builtin_amdgcn_s_setprio(0);

        // causal mask (swapped layout): q = i0+wave*32+mg2*16+l15,
        // kv = jt*64 + ct*16 + quad*4 + rr; only top two kv tiles cross.
        if (jt >= 2 * qt2) {
            #pragma unroll
            for (int mg2 = 0; mg2 < 2; ++mg2) {
                const int gq = i0 + wave * 32 + mg2 * 16 + l15;
                #pragma unroll
                for (int ct = 0; ct < 4; ++ct) {
                    const int gkv0 = jt * 64 + ct * 16 + quad * 4;
                    #pragma unroll
                    for (int rr = 0; rr < 4; ++rr)
                        if (gkv0 + rr > gq) s4t[ct][mg2][rr] = -3.0e38f;
                }
            }
        }

        // P fragments entirely in-register (kv-perm matches vtw2):
        // pa[mg2][frag][j] = exp2(s4t[(j&1)+2*frag][mg2][j>>1])
        bf16x8 pa[2][2];
        #pragma unroll
        for (int mg2 = 0; mg2 < 2; ++mg2)
            #pragma unroll
            for (int j = 0; j < 8; ++j) {
                pa[mg2][0][j] = (bf16)EXP2(s4t[j & 1][mg2][j >> 1]);
                pa[mg2][1][j] = (bf16)EXP2(s4t[2 + (j & 1)][mg2][j >> 1]);
            }

        // PV: each V frag read once, used for both row-groups.
        __builtin_amdgcn_s_setprio(1);
        #pragma unroll
        for (int ht = 0; ht < 4; ++ht) {
            const bf16x8 v0 = *(const bf16x8*)(vb + (0 * 4 + quad) * 512 + (ht * 16 + l15) * 8);
            const bf16x8 v1 = *(const bf16x8*)(vb + (1 * 4 + quad) * 512 + (ht * 16 + l15) * 8);
            #pragma unroll
            for (int mg2 = 0; mg2 < 2; ++mg2) {
                o[mg2][ht] = MFMA16(pa[mg2][0], v0, o[mg2][ht]);
                o[mg2][ht] = MFMA16(pa[mg2][1], v1, o[mg2][ht]);
            }
        }
        #pragma unroll
        for (int mg2 = 0; mg2 < 2; ++mg2) {
            osum[mg2] = MFMA16(pa[mg2][0], vone, osum[mg2]);
            osum[mg2] = MFMA16(pa[mg2][1], vone, osum[mg2]);
        }
        __builtin_amdgcn_s_setprio(0);

        pipe_sync();   // drain prefetch (overlapped by compute), free kvs[c]
    }

    // epilogue: partial O rows L = wave*32 + mg2*16 + quad*4 + rr (O as bf16)
    bf16* pb_o = pbuf_o + (size_t)(((b * 32 + qt2) * 4) + h) * P_O;
    float* pb_l = pbuf_l + (size_t)(((b * 32 + qt2) * 4) + h) * P_L;
    #pragma unroll
    for (int mg2 = 0; mg2 < 2; ++mg2) {
        const int L0 = wave * 32 + mg2 * 16 + quad * 4;
        #pragma unroll
        for (int ht = 0; ht < 4; ++ht)
            #pragma unroll
            for (int rr = 0; rr < 4; ++rr)
                pb_o[(L0 + rr) * 64 + ht * 16 + l15] = (bf16)o[mg2][ht][rr];
        if (l15 == 0) {
            #pragma unroll
            for (int rr = 0; rr < 4; ++rr)
                pb_l[L0 + rr] = osum[mg2][rr];
        }
    }
}

// -------------------------------------------------------------------------
// K3: combine. grid 256 x 256. out = sum_h O_h / sum_h l_h.
// Block = 64 rows of one (b,qt2) 128-row partial set (half = bx&1).
// -------------------------------------------------------------------------
__global__ __launch_bounds__(256) void combine(
    const bf16* __restrict__ pbuf_o, const float* __restrict__ pbuf_l,
    float* __restrict__ out)
{
    const int bq2 = blockIdx.x >> 1, tid = threadIdx.x;
    const int row = ((blockIdx.x & 1) << 6) + (tid >> 2);   // 0..127
    const int c0 = (tid & 3) * 16;

    float a[16] = {};
    float l = 0.f;
    #pragma unroll
    for (int h = 0; h < 4; ++h) {
        const bf16* ph = pbuf_o + (size_t)(bq2 * 4 + h) * P_O + row * 64 + c0;
        const bf16x8 v0 = *(const bf16x8*)ph;
        const bf16x8 v1 = *(const bf16x8*)(ph + 8);
        #pragma unroll
        for (int j = 0; j < 8; ++j) {
            a[j]     += (float)v0[j];
            a[8 + j] += (float)v1[j];
        }
        l += pbuf_l[(size_t)(bq2 * 4 + h) * P_L + row];
    }
    const float inv = 1.0f / l;
    float* op = out + ((size_t)bq2 * 128 + row) * 64 + c0;
    #pragma unroll
    for (int g = 0; g < 4; ++g) {
        f32x4 v = {a[g * 4], a[g * 4 + 1], a[g * 4 + 2], a[g * 4 + 3]};
        *(f32x4*)(op + g * 4) = v * inv;
    }
}

extern "C" void kernel_launch(void* const* d_in, const int* in_sizes, int n_in,
                              void* d_out, int out_size, void* d_ws, size_t ws_size,
                              hipStream_t stream) {
    const float* x  = (const float*)d_in[0];
    const float* Wq = (const float*)d_in[1];
    const float* Wk = (const float*)d_in[2];
    const float* Wv = (const float*)d_in[3];

    bf16* qw   = (bf16*)d_ws;                          // 2 MB, plain [t][h]
    bf16* kw2  = qw + (size_t)M_SZ * H_SZ;             // 2 MB, per-kv-tile slabs
    bf16* vtw2 = kw2 + (size_t)M_SZ * H_SZ;            // 2 MB, kv-permuted slabs
    bf16* wt2  = vtw2 + (size_t)M_SZ * H_SZ;           // 384 KB, per-step slabs
    bf16* pbuf_o = wt2 + 3 * 64 * 1024;                // 8 MB bf16 O partials
    float* pbuf_l = (float*)(pbuf_o + (size_t)512 * P_O);  // 256 KB l partials
    float* out = (float*)d_out;

    wt_prep<<<48, 256, 0, stream>>>(Wq, Wk, Wv, wt2);
    qkv_proj<<<M_SZ / 32, 256, 0, stream>>>(x, wt2, qw, kw2, vtw2);
    flash_attn<<<512, 256, 0, stream>>>(qw, kw2, vtw2, pbuf_o, pbuf_l);
    combine<<<256, 256, 0, stream>>>(pbuf_o, pbuf_l, out);
}

// Round 6
// 141.157 us; speedup vs baseline: 1.0779x; 1.0102x over previous
//
#include <hip/hip_runtime.h>
#include <cstdint>

// Head attention: x[4,4096,1024] fp32, Wq/Wk/Wv[1024,64] fp32 -> out[4,4096,64] fp32.
// Round 15 (on r14): TRUE counted-vmcnt prefetch pipelines (T3/T4 done right).
//  r10/r11's pipe_sync ended with vmcnt(0), draining the just-issued prefetch
//  (no latency ever hidden). Now: issue stage(next); s_waitcnt vmcnt(N_new);
//  s_barrier  -> only the PREVIOUS stage's loads complete, new ones stay in
//  flight across the barrier. Bottom barrier is raw s_barrier (no drain).
//  K1: double-buffered slabs (64KB LDS, 2 blocks/CU), vmcnt(8), tail vmcnt(0).
//  K2: existing dbuf with wait fixed to vmcnt(4), tail vmcnt(0).
//  K0: wt_prep  - W -> bf16 per-64k-step LDS-image slabs; Wq pre-scaled (frozen)
//  K1: qkv_proj - 32-row blocks, BK=64, staggered slab phase, counted-vmcnt dbuf
//  K2: flash    - fat tile (b, qt2-128rows, h4), dbuf 16KB KV slab, in-reg P
//  K3: combine  - out = sum_h O_h / sum_h l_h over bf16 partials (frozen)

typedef __bf16 bf16;
typedef __bf16 bf16x4 __attribute__((ext_vector_type(4)));
typedef __bf16 bf16x8 __attribute__((ext_vector_type(8)));
typedef float  f32x4  __attribute__((ext_vector_type(4)));

#define MFMA16(a, b, c) __builtin_amdgcn_mfma_f32_16x16x32_bf16((a), (b), (c), 0, 0, 0)

#if __has_builtin(__builtin_amdgcn_exp2f)
#define EXP2(x) __builtin_amdgcn_exp2f(x)
#else
#define EXP2(x) exp2f(x)
#endif

#define B_SZ 4
#define T_SZ 4096
#define C_SZ 1024
#define H_SZ 64
#define M_SZ (B_SZ * T_SZ)
#define QSCALE (1.4426950408889634f / 32.0f)   // log2(e)/sqrt(1024)
#define P_O 8192                               // bf16 elems per O-partial (128x64)
#define P_L 128                                // f32 elems per l-partial

// async 16B global->LDS DMA; LDS dest is wave-uniform base + lane*16.
__device__ __forceinline__ void dma16(const void* g, void* l) {
    __builtin_amdgcn_global_load_lds(
        (const __attribute__((address_space(1))) uint32_t*)(uintptr_t)g,
        (__attribute__((address_space(3))) uint32_t*)(uint32_t)(uintptr_t)l,
        16, 0, 0);
}

// top-of-iter: counted wait (leave N newest loads in flight) + join barrier.
#define WAIT_BARRIER(N) do {                                       \
    asm volatile("s_waitcnt vmcnt(" #N ")" ::: "memory");          \
    __builtin_amdgcn_s_barrier();                                  \
    __builtin_amdgcn_sched_barrier(0);                             \
} while (0)

// bottom-of-iter: raw barrier (NO vmcnt drain -- prefetch stays in flight).
#define BOT_BARRIER() do {                                         \
    __builtin_amdgcn_sched_barrier(0);                             \
    __builtin_amdgcn_s_barrier();                                  \
    __builtin_amdgcn_sched_barrier(0);                             \
} while (0)

// -------------------------------------------------------------------------
// K0: wt2 image, per 64-k outer step s: elem off =
//   s*12288 + sub*6144 + quad*1536 + n*8 + j  (k = s*64+sub*32+quad*8+j, n = 0..191).
// -------------------------------------------------------------------------
__global__ __launch_bounds__(256) void wt_prep(
    const float* __restrict__ Wq, const float* __restrict__ Wk,
    const float* __restrict__ Wv, bf16* __restrict__ wt2)
{
    const int n4 = blockIdx.x, t = threadIdx.x;
    const int nbase = n4 * 4;
    const float* W = (nbase < 64) ? Wq : (nbase < 128 ? Wk : Wv);
    const float sc = (nbase < 64) ? QSCALE : 1.0f;
    const int ncol = nbase & 63;
    #pragma unroll
    for (int i = 0; i < 4; ++i) {
        const int k = i * 256 + t;
        const float4 v = *(const float4*)(W + (size_t)k * H_SZ + ncol);
        const float vals[4] = {v.x, v.y, v.z, v.w};
        const size_t base = (size_t)(k >> 6) * 12288 + (size_t)((k >> 5) & 1) * 6144
                          + (size_t)((k >> 3) & 3) * 1536 + (k & 7);
        #pragma unroll
        for (int m = 0; m < 4; ++m)
            wt2[base + (size_t)(nbase + m) * 8] = (bf16)(vals[m] * sc);
    }
}

// -------------------------------------------------------------------------
// K1: qkv. grid 512 x 256 (4 waves). Block = 32 rows x 192 fused cols.
// 16 steps of BK=64, slab phase staggered by block. Double-buffered slabs
// (x 8KB + W 24KB per buffer, 64KB total): per step issue next stage's 8
// DMAs, wait vmcnt(8) (= previous stage done, new in flight), barrier,
// compute, raw barrier. Tail step waits vmcnt(0).
// -------------------------------------------------------------------------
__global__ __launch_bounds__(256) void qkv_proj(
    const float* __restrict__ x, const bf16* __restrict__ wt2,
    bf16* __restrict__ qw, bf16* __restrict__ kw2, bf16* __restrict__ vtw2)
{
    const int m0 = blockIdx.x * 32;
    const int tid = threadIdx.x;
    const int wave = tid >> 6, lane = tid & 63;
    const int quad = lane >> 4, l15 = lane & 15;
    const int phase = blockIdx.x & 15;             // slab-phase stagger

    __shared__ __align__(16) float xs[2][2 * 4 * 32 * 8];   // 2 x 8 KB
    __shared__ __align__(16) bf16  ws[2][2 * 4 * 192 * 8];  // 2 x 24 KB

    f32x4 acc[2][3] = {};                          // [mg][ntile]

    // x DMA granule (per thread, i in {0,1}): sub=i, quad=(tid>>6)&3,
    // row=(tid>>1)&31, half=tid&1. k-offset within step: sub*128B+quad*32B+half*16B.
    const char* xg = (const char*)x
        + (size_t)(m0 + ((tid >> 1) & 31)) * 4096
        + (size_t)((tid >> 6) & 3) * 32 + (size_t)(tid & 1) * 16;
    const char* wg = (const char*)wt2 + (size_t)tid * 16;

    auto stage = [&](int s, int buf) {
        const size_t se = (size_t)((s + phase) & 15);
        char* xl = (char*)(&xs[buf][0]) + (size_t)tid * 16;
        char* wl = (char*)(&ws[buf][0]) + (size_t)tid * 16;
        dma16(xg + se * 256, xl);
        dma16(xg + se * 256 + 128, xl + 4096);
        #pragma unroll
        for (int i = 0; i < 6; ++i)
            dma16(wg + se * 24576 + (size_t)i * 4096, wl + (size_t)i * 4096);
    };

    stage(0, 0);

    for (int s = 0; s < 16; ++s) {
        if (s < 15) {
            stage(s + 1, (s + 1) & 1);             // 8 new DMAs in flight
            WAIT_BARRIER(8);                       // previous stage complete
        } else {
            WAIT_BARRIER(0);                       // tail: drain last stage
        }
        const float* xb = &xs[s & 1][0];
        const bf16*  wb = &ws[s & 1][0];

        #pragma unroll
        for (int ss = 0; ss < 2; ++ss) {
            bf16x8 a[2];
            #pragma unroll
            for (int mg = 0; mg < 2; ++mg) {
                const float* ap = xb + ss * 1024 + quad * 256 + (mg * 16 + l15) * 8;
                const f32x4 lo = *(const f32x4*)ap;
                const f32x4 hi = *(const f32x4*)(ap + 4);
                a[mg][0] = (bf16)lo[0]; a[mg][1] = (bf16)lo[1];
                a[mg][2] = (bf16)lo[2]; a[mg][3] = (bf16)lo[3];
                a[mg][4] = (bf16)hi[0]; a[mg][5] = (bf16)hi[1];
                a[mg][6] = (bf16)hi[2]; a[mg][7] = (bf16)hi[3];
            }
            #pragma unroll
            for (int i = 0; i < 3; ++i) {
                const int nt = wave * 3 + i;
                const bf16x8 wf = *(const bf16x8*)(wb + ss * 6144 + quad * 1536
                                                   + (nt * 16 + l15) * 8);
                #pragma unroll
                for (int mg = 0; mg < 2; ++mg)
                    acc[mg][i] = MFMA16(a[mg], wf, acc[mg][i]);
            }
        }

        BOT_BARRIER();   // reads of buf[s&1] done before it is re-staged
    }

    // epilogue: row t = m0+mg*16+quad*4+r, col n = (wave*3+i)*16+l15
    #pragma unroll
    for (int mg = 0; mg < 2; ++mg)
        #pragma unroll
        for (int i = 0; i < 3; ++i) {
            const int n = (wave * 3 + i) * 16 + l15;
            const int which = n >> 6, col = n & 63;
            #pragma unroll
            for (int r = 0; r < 4; ++r) {
                const int t = m0 + mg * 16 + quad * 4 + r;
                const bf16 v = (bf16)acc[mg][i][r];
                if (which == 0) {
                    qw[(size_t)t * H_SZ + col] = v;
                } else if (which == 1) {
                    // K slab: jt*4096 + ((col>>5)*4 + ((col>>3)&3))*512 + (t&63)*8 + (col&7)
                    kw2[(size_t)(t >> 6) * 4096
                        + (size_t)(((col >> 5) << 2) + ((col >> 3) & 3)) * 512
                        + (size_t)(t & 63) * 8 + (col & 7)] = v;
                } else {
                    // V slab, kv-permuted for in-register P:
                    // p = ((t6>>2)&3)*8 + (t6&3)*2 + ((t6>>4)&1) + (t6>>5)*32
                    const int t6 = t & 63;
                    const int p = ((t6 >> 2) & 3) * 8 + (t6 & 3) * 2
                                + ((t6 >> 4) & 1) + (t6 >> 5) * 32;
                    vtw2[(size_t)(t >> 6) * 4096
                         + (size_t)(p >> 3) * 512 + (size_t)col * 8 + (p & 7)] = v;
                }
            }
        }
}

// -------------------------------------------------------------------------
// K2: causal flash, fat tile, in-register P. grid 512 x 256.
// Item (b, qt2 in 0..31, h in 0..3): 128 q-rows, 4 waves x 32 rows.
// QK swapped: s4t[ct][mg2] = MFMA16(K, Q) -> lane (quad,l15) holds
// P^T elems q = mg2*16+l15, kv = ct*16+quad*4+rr. With vtw2's kv-perm,
// pa[mg2][frag][j] = exp2(s4t[(j&1)+2*frag][mg2][j>>1]) -- no LDS for P.
// Double-buffered 16KB KV slab; counted vmcnt(4) wait (prefetch in flight).
// Partials: O bf16 (128x64) -> pbuf_o, l f32 (128) -> pbuf_l.
// -------------------------------------------------------------------------
__global__ __launch_bounds__(256) void flash_attn(
    const bf16* __restrict__ qw, const bf16* __restrict__ kw2,
    const bf16* __restrict__ vtw2, bf16* __restrict__ pbuf_o,
    float* __restrict__ pbuf_l)
{
    const int bx = blockIdx.x;
    const int item = (bx & 1) ? (511 - (bx >> 1)) : (bx >> 1);  // serpentine
    const int qt2 = 31 - (item >> 4);                           // heavy first
    const int b   = (item >> 2) & 3;
    const int h   = item & 3;
    const int i0  = qt2 * 128;
    const int nkv = qt2 * 2 + 2;     // kv tiles 0..2*qt2+1 cover the 128 q-rows

    const int tid = threadIdx.x;
    const int wave = tid >> 6, lane = tid & 63;
    const int quad = lane >> 4, l15 = lane & 15;

    __shared__ __align__(16) bf16 kvs[2][8192];      // 2 x 16 KB: K 8K | V 8K

    // Q frags (B-operand role): rows i0 + wave*32 + mg2*16 + l15, head quad*8 (+32)
    bf16x8 aq[2][2];
    #pragma unroll
    for (int mg2 = 0; mg2 < 2; ++mg2) {
        const bf16* qp = qw + ((size_t)b * T_SZ + i0 + wave * 32 + mg2 * 16 + l15) * H_SZ
                       + quad * 8;
        aq[mg2][0] = *(const bf16x8*)qp;
        aq[mg2][1] = *(const bf16x8*)(qp + 32);
    }
    const bf16 onev = (bf16)1.0f;
    const bf16x8 vone = {onev, onev, onev, onev, onev, onev, onev, onev};

    const char* kgb = (const char*)kw2 + (size_t)b * 524288;
    const char* vgb = (const char*)vtw2 + (size_t)b * 524288;

    f32x4 o[2][4] = {};
    f32x4 osum[2] = {};

    auto stage = [&](int jt, int buf) {
        const char* ks = kgb + (size_t)jt * 8192;
        const char* vs = vgb + (size_t)jt * 8192;
        char* dst = (char*)(&kvs[buf][0]) + (size_t)tid * 16;
        dma16(ks + (size_t)tid * 16, dst);
        dma16(ks + 4096 + (size_t)tid * 16, dst + 4096);
        dma16(vs + (size_t)tid * 16, dst + 8192);
        dma16(vs + 4096 + (size_t)tid * 16, dst + 12288);
    };

    if (h < nkv) stage(h, 0);

    int c = 0;
    for (int jt = h; jt < nkv; jt += 4, c ^= 1) {
        if (jt + 4 < nkv) {
            stage(jt + 4, c ^ 1);                  // 4 new DMAs in flight
            WAIT_BARRIER(4);                       // previous stage complete
        } else {
            WAIT_BARRIER(0);                       // tail: drain last stage
        }
        const bf16* kb = &kvs[c][0];
        const bf16* vb = &kvs[c][0] + 4096;

        // QK swapped: A = K-frag (rows = kv), B = Q-frag (cols = q).
        f32x4 s4t[4][2] = {};                      // [ct][mg2]
        __builtin_amdgcn_s_setprio(1);
        #pragma unroll
        for (int ct = 0; ct < 4; ++ct) {
            const bf16x8 k0 = *(const bf16x8*)(kb + (0 * 4 + quad) * 512 + (ct * 16 + l15) * 8);
            const bf16x8 k1 = *(const bf16x8*)(kb + (1 * 4 + quad) * 512 + (ct * 16 + l15) * 8);
            #pragma unroll
            for (int mg2 = 0; mg2 < 2; ++mg2) {
                s4t[ct][mg2] = MFMA16(k0, aq[mg2][0], s4t[ct][mg2]);
                s4t[ct][mg2] = MFMA16(k1, aq[mg2][1], s4t[ct][mg2]);
            }
        }
        __builtin_amdgcn_s_setprio(0);

        // causal mask (swapped layout): q = i0+wave*32+mg2*16+l15,
        // kv = jt*64 + ct*16 + quad*4 + rr; only top two kv tiles cross.
        if (jt >= 2 * qt2) {
            #pragma unroll
            for (int mg2 = 0; mg2 < 2; ++mg2) {
                const int gq = i0 + wave * 32 + mg2 * 16 + l15;
                #pragma unroll
                for (int ct = 0; ct < 4; ++ct) {
                    const int gkv0 = jt * 64 + ct * 16 + quad * 4;
                    #pragma unroll
                    for (int rr = 0; rr < 4; ++rr)
                        if (gkv0 + rr > gq) s4t[ct][mg2][rr] = -3.0e38f;
                }
            }
        }

        // P fragments entirely in-register (kv-perm matches vtw2):
        // pa[mg2][frag][j] = exp2(s4t[(j&1)+2*frag][mg2][j>>1])
        bf16x8 pa[2][2];
        #pragma unroll
        for (int mg2 = 0; mg2 < 2; ++mg2)
            #pragma unroll
            for (int j = 0; j < 8; ++j) {
                pa[mg2][0][j] = (bf16)EXP2(s4t[j & 1][mg2][j >> 1]);
                pa[mg2][1][j] = (bf16)EXP2(s4t[2 + (j & 1)][mg2][j >> 1]);
            }

        // PV: each V frag read once, used for both row-groups.
        __builtin_amdgcn_s_setprio(1);
        #pragma unroll
        for (int ht = 0; ht < 4; ++ht) {
            const bf16x8 v0 = *(const bf16x8*)(vb + (0 * 4 + quad) * 512 + (ht * 16 + l15) * 8);
            const bf16x8 v1 = *(const bf16x8*)(vb + (1 * 4 + quad) * 512 + (ht * 16 + l15) * 8);
            #pragma unroll
            for (int mg2 = 0; mg2 < 2; ++mg2) {
                o[mg2][ht] = MFMA16(pa[mg2][0], v0, o[mg2][ht]);
                o[mg2][ht] = MFMA16(pa[mg2][1], v1, o[mg2][ht]);
            }
        }
        #pragma unroll
        for (int mg2 = 0; mg2 < 2; ++mg2) {
            osum[mg2] = MFMA16(pa[mg2][0], vone, osum[mg2]);
            osum[mg2] = MFMA16(pa[mg2][1], vone, osum[mg2]);
        }
        __builtin_amdgcn_s_setprio(0);

        BOT_BARRIER();   // reads of kvs[c] done before it is re-staged
    }

    // epilogue: partial O rows L = wave*32 + mg2*16 + quad*4 + rr (O as bf16)
    bf16* pb_o = pbuf_o + (size_t)(((b * 32 + qt2) * 4) + h) * P_O;
    float* pb_l = pbuf_l + (size_t)(((b * 32 + qt2) * 4) + h) * P_L;
    #pragma unroll
    for (int mg2 = 0; mg2 < 2; ++mg2) {
        const int L0 = wave * 32 + mg2 * 16 + quad * 4;
        #pragma unroll
        for (int ht = 0; ht < 4; ++ht)
            #pragma unroll
            for (int rr = 0; rr < 4; ++rr)
                pb_o[(L0 + rr) * 64 + ht * 16 + l15] = (bf16)o[mg2][ht][rr];
        if (l15 == 0) {
            #pragma unroll
            for (int rr = 0; rr < 4; ++rr)
                pb_l[L0 + rr] = osum[mg2][rr];
        }
    }
}

// -------------------------------------------------------------------------
// K3: combine. grid 256 x 256. out = sum_h O_h / sum_h l_h.
// Block = 64 rows of one (b,qt2) 128-row partial set (half = bx&1).
// -------------------------------------------------------------------------
__global__ __launch_bounds__(256) void combine(
    const bf16* __restrict__ pbuf_o, const float* __restrict__ pbuf_l,
    float* __restrict__ out)
{
    const int bq2 = blockIdx.x >> 1, tid = threadIdx.x;
    const int row = ((blockIdx.x & 1) << 6) + (tid >> 2);   // 0..127
    const int c0 = (tid & 3) * 16;

    float a[16] = {};
    float l = 0.f;
    #pragma unroll
    for (int h = 0; h < 4; ++h) {
        const bf16* ph = pbuf_o + (size_t)(bq2 * 4 + h) * P_O + row * 64 + c0;
        const bf16x8 v0 = *(const bf16x8*)ph;
        const bf16x8 v1 = *(const bf16x8*)(ph + 8);
        #pragma unroll
        for (int j = 0; j < 8; ++j) {
            a[j]     += (float)v0[j];
            a[8 + j] += (float)v1[j];
        }
        l += pbuf_l[(size_t)(bq2 * 4 + h) * P_L + row];
    }
    const float inv = 1.0f / l;
    float* op = out + ((size_t)bq2 * 128 + row) * 64 + c0;
    #pragma unroll
    for (int g = 0; g < 4; ++g) {
        f32x4 v = {a[g * 4], a[g * 4 + 1], a[g * 4 + 2], a[g * 4 + 3]};
        *(f32x4*)(op + g * 4) = v * inv;
    }
}

extern "C" void kernel_launch(void* const* d_in, const int* in_sizes, int n_in,
                              void* d_out, int out_size, void* d_ws, size_t ws_size,
                              hipStream_t stream) {
    const float* x  = (const float*)d_in[0];
    const float* Wq = (const float*)d_in[1];
    const float* Wk = (const float*)d_in[2];
    const float* Wv = (const float*)d_in[3];

    bf16* qw   = (bf16*)d_ws;                          // 2 MB, plain [t][h]
    bf16* kw2  = qw + (size_t)M_SZ * H_SZ;             // 2 MB, per-kv-tile slabs
    bf16* vtw2 = kw2 + (size_t)M_SZ * H_SZ;            // 2 MB, kv-permuted slabs
    bf16* wt2  = vtw2 + (size_t)M_SZ * H_SZ;           // 384 KB, per-step slabs
    bf16* pbuf_o = wt2 + 3 * 64 * 1024;                // 8 MB bf16 O partials
    float* pbuf_l = (float*)(pbuf_o + (size_t)512 * P_O);  // 256 KB l partials
    float* out = (float*)d_out;

    wt_prep<<<48, 256, 0, stream>>>(Wq, Wk, Wv, wt2);
    qkv_proj<<<M_SZ / 32, 256, 0, stream>>>(x, wt2, qw, kw2, vtw2);
    flash_attn<<<512, 256, 0, stream>>>(qw, kw2, vtw2, pbuf_o, pbuf_l);
    combine<<<256, 256, 0, stream>>>(pbuf_o, pbuf_l, out);
}